// Round 9
// baseline (3701.225 us; speedup 1.0000x reference)
//
#include <hip/hip_runtime.h>
#include <cstdint>
#include <math.h>

#define NPTS 8192
#define NB 4
#define NG 2048
#define NK 32
#define CIN 96
#define COUT 192

typedef unsigned long long ull;

// ---------------- setup: SoA transpose + |p|^2 (bit-exact vs ref dst2) ----------------
__global__ __launch_bounds__(256) void setup_kernel(const float* __restrict__ xyz,
                                                    float* __restrict__ xs, float* __restrict__ ys,
                                                    float* __restrict__ zs, float* __restrict__ d2){
  int i = blockIdx.x*256 + threadIdx.x;
  if (i >= NB*NPTS) return;
  float x = xyz[3*i+0], y = xyz[3*i+1], z = xyz[3*i+2];
  xs[i]=x; ys[i]=y; zs[i]=z;
  d2[i] = __fadd_rn(__fadd_rn(__fmul_rn(x,x),__fmul_rn(y,y)),__fmul_rn(z,z));
}

__device__ __forceinline__ ull umax64(ull a, ull b){ return (a>b)?a:b; }

// DPP u64 max reduce step (both halves moved with same ctrl -> same source lane)
template<int CTRL>
__device__ __forceinline__ ull dppmax64(ull v){
  unsigned lo=(unsigned)v, hi=(unsigned)(v>>32);
  unsigned olo=(unsigned)__builtin_amdgcn_update_dpp((int)lo,(int)lo,CTRL,0xf,0xf,false);
  unsigned ohi=(unsigned)__builtin_amdgcn_update_dpp((int)hi,(int)hi,CTRL,0xf,0xf,false);
  ull o=((ull)ohi<<32)|(ull)olo;
  return (o>v)?o:v;
}
__device__ __forceinline__ ull wavemax64(ull v){   // result valid in lane 63
  v=dppmax64<0x111>(v); v=dppmax64<0x112>(v); v=dppmax64<0x114>(v);
  v=dppmax64<0x118>(v); v=dppmax64<0x142>(v); v=dppmax64<0x143>(v);
  return v;
}

// LDS layout offsets (bytes)
#define OFF_X    0        // float[8192]
#define OFF_Y    32768
#define OFF_Z    65536
#define OFF_D    98304    // float[8192]
#define OFF_ORG  131072   // u16[8192]
#define OFF_K    147456   // ull[2][128]
#define OFF_BBC  149504   // float[128][8] (bbox, 2 pad)
#define OFF_HIST 153600   // int[512]
#define OFF_BBS  155648   // float[48]
#define FPS_LDS  155840

// ---------------- FPS: LDS-resident D + per-chunk cached max keys ---------------------
// 128 Morton-sorted chunks of 64 pts. Per round, per wave: lane l tests bboxes of
// chunks l and 64+l (registers) against each chunk's OWN cached max (LDS key) ->
// ballot -> uniform scalar ffs loop assigns active chunks rank%8==w -> only assigned
// chunks updated (LDS D) + one wavemax64 each -> key into double-buffered Karr;
// inactive chunk keys copied (8B) by static owner. ONE barrier; winner = reduce of
// 128 cached keys. All skipped work costs ~0. Exact: margin 1e-4 >> fp error; same
// distance arithmetic (contract off) and (maxD, lowest-orig) tie-break as prior rounds.
__global__ __launch_bounds__(512,2) void fps_kernel(const float* __restrict__ xyz, int* __restrict__ fps_idx){
#pragma clang fp contract(off)   // selection-critical: no fma contraction anywhere here
  extern __shared__ char smem[];
  float* X   = (float*)(smem + OFF_X);
  float* Y   = (float*)(smem + OFF_Y);
  float* Z   = (float*)(smem + OFF_Z);
  float* Dar = (float*)(smem + OFF_D);
  unsigned short* ORG = (unsigned short*)(smem + OFF_ORG);
  ull*   Karr = (ull*)(smem + OFF_K);          // [2][128]
  float* bbc  = (float*)(smem + OFF_BBC);      // [128][8]
  int*   hist = (int*)(smem + OFF_HIST);
  float* bbs  = (float*)(smem + OFF_BBS);
  const int b = blockIdx.x, t = threadIdx.x;
  const int w = t>>6, lane = t&63;
  const float* base = xyz + (size_t)b*NPTS*3;

  // ---- init: load originals, global bbox, Morton cells, scatter-sort into LDS SoA ----
  float ox[16], oy[16], oz[16];
#pragma unroll
  for (int j=0;j<16;++j){
    int p = t + 512*j;
    ox[j]=base[3*p+0]; oy[j]=base[3*p+1]; oz[j]=base[3*p+2];
  }
  float mnx=ox[0],mxx=ox[0],mny=oy[0],mxy=oy[0],mnz=oz[0],mxz=oz[0];
#pragma unroll
  for (int j=1;j<16;++j){
    mnx=fminf(mnx,ox[j]); mxx=fmaxf(mxx,ox[j]);
    mny=fminf(mny,oy[j]); mxy=fmaxf(mxy,oy[j]);
    mnz=fminf(mnz,oz[j]); mxz=fmaxf(mxz,oz[j]);
  }
#pragma unroll
  for (int off=32; off>0; off>>=1){
    mnx=fminf(mnx,__shfl_xor(mnx,off)); mxx=fmaxf(mxx,__shfl_xor(mxx,off));
    mny=fminf(mny,__shfl_xor(mny,off)); mxy=fmaxf(mxy,__shfl_xor(mxy,off));
    mnz=fminf(mnz,__shfl_xor(mnz,off)); mxz=fmaxf(mxz,__shfl_xor(mxz,off));
  }
  hist[t] = 0;
  if (t < 128) Karr[128 + t] = ((ull)__float_as_uint(1e10f))<<32;  // buf1 init (round-0 thresholds)
  if (lane==0){
    bbs[w*6+0]=mnx; bbs[w*6+1]=mxx; bbs[w*6+2]=mny;
    bbs[w*6+3]=mxy; bbs[w*6+4]=mnz; bbs[w*6+5]=mxz;
  }
  if (t==0) fps_idx[b*NG] = 0;
  __syncthreads();
  float gx0=1e30f,gx1=-1e30f,gy0=1e30f,gy1=-1e30f,gz0=1e30f,gz1=-1e30f;
  for (int q=0;q<8;++q){
    gx0=fminf(gx0,bbs[q*6+0]); gx1=fmaxf(gx1,bbs[q*6+1]);
    gy0=fminf(gy0,bbs[q*6+2]); gy1=fmaxf(gy1,bbs[q*6+3]);
    gz0=fminf(gz0,bbs[q*6+4]); gz1=fmaxf(gz1,bbs[q*6+5]);
  }
  const float sxv = 8.0f/fmaxf(gx1-gx0,1e-20f);
  const float syv = 8.0f/fmaxf(gy1-gy0,1e-20f);
  const float szv = 8.0f/fmaxf(gz1-gz0,1e-20f);
  int cell[16];
#pragma unroll
  for (int j=0;j<16;++j){
    int cx = min(7,(int)((ox[j]-gx0)*sxv));
    int cy = min(7,(int)((oy[j]-gy0)*syv));
    int cz = min(7,(int)((oz[j]-gz0)*szv));
    int m = (cx&1) | ((cy&1)<<1) | ((cz&1)<<2)
          | ((cx&2)<<2) | ((cy&2)<<3) | ((cz&2)<<4)
          | ((cx&4)<<4) | ((cy&4)<<5) | ((cz&4)<<6);
    cell[j]=m;
    atomicAdd(&hist[m],1);
  }
  __syncthreads();
  if (t==0){
    int run=0;
    for (int c=0;c<512;++c){ int h=hist[c]; hist[c]=run; run+=h; }
  }
  __syncthreads();
#pragma unroll
  for (int j=0;j<16;++j){
    int pos = atomicAdd(&hist[cell[j]],1);
    X[pos]=ox[j]; Y[pos]=oy[j]; Z[pos]=oz[j];
    ORG[pos]=(unsigned short)(t+512*j);
    Dar[pos]=1e10f;                                 // ref init
  }
  __syncthreads();
  // per-chunk bboxes: wave w computes chunks 16w..16w+15 from LDS, writes bbc
  for (int j=0;j<16;++j){
    int c = (w<<4)+j, pos=(c<<6)+lane;
    float a0=X[pos],a1=a0, b0=Y[pos],b1=b0, c0=Z[pos],c1=c0;
#pragma unroll
    for (int off=32; off>0; off>>=1){
      a0=fminf(a0,__shfl_xor(a0,off)); a1=fmaxf(a1,__shfl_xor(a1,off));
      b0=fminf(b0,__shfl_xor(b0,off)); b1=fmaxf(b1,__shfl_xor(b1,off));
      c0=fminf(c0,__shfl_xor(c0,off)); c1=fmaxf(c1,__shfl_xor(c1,off));
    }
    if (lane==0){
      float* o = bbc + c*8;
      o[0]=a0; o[1]=a1; o[2]=b0; o[3]=b1; o[4]=c0; o[5]=c1; o[6]=0.f; o[7]=0.f;
    }
  }
  __syncthreads();
  // lane's two chunk bboxes in registers: chunk A=lane, chunk B=64+lane
  float A0,A1,A2,A3,A4,A5, B0,B1,B2,B3,B4,B5;
  { const float* o = bbc + lane*8;
    A0=o[0];A1=o[1];A2=o[2];A3=o[3];A4=o[4];A5=o[5];
    const float* p = bbc + (64+lane)*8;
    B0=p[0];B1=p[1];B2=p[2];B3=p[3];B4=p[4];B5=p[5]; }

  // ---- serial rounds ----
  float lx=base[0], ly=base[1], lz=base[2];            // seed = point 0
  for (int it=0; it<NG-1; ++it){
    ull* Knew = Karr + (it&1)*128;
    const ull* Kold = Karr + ((it+1)&1)*128;
    // per-chunk threshold = that chunk's own cached max (tighter than wave/global max)
    ull kA = Kold[lane], kB = Kold[64+lane];
    float thrA = __int_as_float((int)(kA>>32)) * 1.0001f;
    float thrB = __int_as_float((int)(kB>>32)) * 1.0001f;
    float qx,qy,qz,ddx,ddy,ddz,LA,LBv;
    qx=fminf(fmaxf(lx,A0),A1); qy=fminf(fmaxf(ly,A2),A3); qz=fminf(fmaxf(lz,A4),A5);
    ddx=qx-lx; ddy=qy-ly; ddz=qz-lz; LA=(ddx*ddx+ddy*ddy)+ddz*ddz;
    qx=fminf(fmaxf(lx,B0),B1); qy=fminf(fmaxf(ly,B2),B3); qz=fminf(fmaxf(lz,B4),B5);
    ddx=qx-lx; ddy=qy-ly; ddz=qz-lz; LBv=(ddx*ddx+ddy*ddy)+ddz*ddz;
    ull mA = __ballot(LA <= thrA);
    ull mB = __ballot(LBv <= thrB);
    // copy inactive static chunks' keys (8B each) old->new buffer
    if (lane < 16){
      int c = (w<<4) + lane;
      ull msel = (w<4)? mA : mB;
      if (!((msel >> (c&63)) & 1ull)) Knew[c] = Kold[c];
    }
    // uniform scalar scan: active chunks assigned round-robin rank%8 == w
    int r = 0;
    ull m0 = mA;
    while (m0){
      int c = __ffsll(m0) - 1;
      m0 &= (m0 - 1);
      if ((r & 7) == w){
        int pos = (c<<6)|lane;
        float x=X[pos], y=Y[pos], z=Z[pos], Do=Dar[pos];
        float dx=x-lx, dy=y-ly, dz=z-lz;
        float d=(dx*dx+dy*dy)+dz*dz;
        float Dn=fminf(Do,d);
        Dar[pos]=Dn;
        unsigned orig=ORG[pos];
        unsigned lowb=((8191u-orig)<<13)|(unsigned)pos;
        ull key=(((ull)__float_as_uint(Dn))<<32)|(ull)lowb;
        key=wavemax64(key);
        if (lane==63) Knew[c]=key;
      }
      ++r;
    }
    ull m1 = mB;
    while (m1){
      int c = 64 + __ffsll(m1) - 1;
      m1 &= (m1 - 1);
      if ((r & 7) == w){
        int pos = (c<<6)|lane;
        float x=X[pos], y=Y[pos], z=Z[pos], Do=Dar[pos];
        float dx=x-lx, dy=y-ly, dz=z-lz;
        float d=(dx*dx+dy*dy)+dz*dz;
        float Dn=fminf(Do,d);
        Dar[pos]=Dn;
        unsigned orig=ORG[pos];
        unsigned lowb=((8191u-orig)<<13)|(unsigned)pos;
        ull key=(((ull)__float_as_uint(Dn))<<32)|(ull)lowb;
        key=wavemax64(key);
        if (lane==63) Knew[c]=key;
      }
      ++r;
    }
    __syncthreads();                                   // ONE barrier per round
    // global winner = max over 128 cached chunk keys
    ull a = Knew[lane], b2 = Knew[64+lane];
    ull k = wavemax64(umax64(a,b2));
    unsigned khi = (unsigned)__builtin_amdgcn_readlane((int)(k>>32),63);
    unsigned klo = (unsigned)__builtin_amdgcn_readlane((int)k,63);
    (void)khi;
    unsigned pos = klo & 0x1FFFu;
    lx = X[pos]; ly = Y[pos]; lz = Z[pos];             // broadcast reads
    if (t==0) fps_idx[b*NG + it + 1] = (int)(8191u - ((klo>>13)&0x1FFFu));
  }
}

// ---------------- kNN: wave-wide exact top-32 (lexicographic (d,idx)) ----------------
__device__ __forceinline__ bool lexlt(float ad, int ai, float bd, int bi){
  return (ad < bd) || ((ad == bd) && (ai < bi));
}
__device__ __forceinline__ void sort_desc(float& d, int& i, int lane){
#pragma unroll
  for (int k=2;k<=64;k<<=1){
#pragma unroll
    for (int j=k>>1;j>0;j>>=1){
      float od = __shfl_xor(d, j);
      int   oi = __shfl_xor(i, j);
      bool dirUp = (lane & k) != 0;      // flipped -> overall descending
      bool lower = (lane & j) == 0;
      bool less  = lexlt(d,i,od,oi);
      bool keep  = (less == (lower == dirUp));
      if (!keep){ d=od; i=oi; }
    }
  }
}
__device__ __forceinline__ void merge_asc(float& d, int& i, int lane){
#pragma unroll
  for (int j=32;j>0;j>>=1){
    float od = __shfl_xor(d, j);
    int   oi = __shfl_xor(i, j);
    bool lower = (lane & j) == 0;
    bool less  = lexlt(d,i,od,oi);
    bool keep  = (less == lower);
    if (!keep){ d=od; i=oi; }
  }
}

__global__ __launch_bounds__(256) void knn_kernel(const float* __restrict__ xs, const float* __restrict__ ys,
                                                  const float* __restrict__ zs, const float* __restrict__ d2,
                                                  const int* __restrict__ fps_idx, int* __restrict__ knn_out){
  __shared__ float tx[256], ty[256], tz[256], td[256];
  const int tid = threadIdx.x;
  const int wid = tid>>6, lane = tid&63;
  const int pid = blockIdx.x*4 + wid;     // b*NG+g
  const int b = pid >> 11;
  const float* bx = xs + b*NPTS;
  const float* by = ys + b*NPTS;
  const float* bz = zs + b*NPTS;
  const float* bD = d2 + b*NPTS;
  const int fi = fps_idx[pid];
  const float ax = bx[fi], ay = by[fi], az = bz[fi];
  const float src2 = __fadd_rn(__fadd_rn(__fmul_rn(ax,ax),__fmul_rn(ay,ay)),__fmul_rn(az,az));
  float Ad = INFINITY; int Ai = 0x7fffffff;      // sorted-ascending top-64 (1/lane)
  float tau_d = INFINITY; int tau_i = 0x7fffffff; // current exact 32nd smallest
  for (int s=0; s<NPTS/256; ++s){
    __syncthreads();
    int gidx = s*256 + tid;
    tx[tid]=bx[gidx]; ty[tid]=by[gidx]; tz[tid]=bz[gidx]; td[tid]=bD[gidx];
    __syncthreads();
    float m0,m1,m2,m3; int i0,i1,i2,i3;
#define LOADJ(mj, ij, J) { int li = (J)*64 + lane; \
    float dot = __fadd_rn(__fadd_rn(__fmul_rn(ax,tx[li]),__fmul_rn(ay,ty[li])),__fmul_rn(az,tz[li])); \
    mj = __fadd_rn(__fadd_rn(__fmul_rn(-2.0f,dot), src2), td[li]); ij = s*256 + li; }
    LOADJ(m0,i0,0) LOADJ(m1,i1,1) LOADJ(m2,i2,2) LOADJ(m3,i3,3)
#undef LOADJ
    while (true){
      bool any = lexlt(m0,i0,tau_d,tau_i) || lexlt(m1,i1,tau_d,tau_i) ||
                 lexlt(m2,i2,tau_d,tau_i) || lexlt(m3,i3,tau_d,tau_i);
      if (__ballot(any) == 0ull) break;
      float cd = m0; int ci = i0; int sel = 0;
      if (lexlt(m1,i1,cd,ci)){ cd=m1; ci=i1; sel=1; }
      if (lexlt(m2,i2,cd,ci)){ cd=m2; ci=i2; sel=2; }
      if (lexlt(m3,i3,cd,ci)){ cd=m3; ci=i3; sel=3; }
      if      (sel==0) m0=INFINITY;
      else if (sel==1) m1=INFINITY;
      else if (sel==2) m2=INFINITY;
      else             m3=INFINITY;
      sort_desc(cd, ci, lane);                    // new chunk descending
      if (lexlt(cd,ci,Ad,Ai)){ Ad=cd; Ai=ci; }    // elementwise min -> bitonic
      merge_asc(Ad, Ai, lane);                    // re-sort ascending
      tau_d = __shfl(Ad, 31);
      tau_i = __shfl(Ai, 31);
    }
  }
  if (lane < NK) knn_out[pid*NK + lane] = Ai;
}

// ---------------- global stats (fp64 partials per block) ----------------
__global__ __launch_bounds__(256) void stats_kernel(const float* __restrict__ x, const float* __restrict__ xyz,
                                                    const int* __restrict__ fps_idx, const int* __restrict__ knn,
                                                    double* __restrict__ partials){
  const int tid=threadIdx.x, wid=tid>>6, lane=tid&63;
  const int pid = blockIdx.x*4 + wid;
  const int b = pid>>11;
  const int fi = fps_idx[pid];
  const float* xb = x + (size_t)b*NPTS*CIN;
  const float* zb = xyz + (size_t)b*NPTS*3;
  const float lc0 = xb[fi*CIN + lane];
  float lc1 = 0.f; if (lane<32) lc1 = xb[fi*CIN + 64 + lane];
  float czv = 0.f; if (lane<3)  czv = zb[fi*3 + lane];
  double s1=0.0, s2=0.0, a1=0.0, a2=0.0;
  for (int k=0;k<NK;++k){
    int idx = knn[pid*NK + k];
    float d0 = __fsub_rn(xb[idx*CIN + lane], lc0);
    s1 += (double)d0; s2 += (double)d0*(double)d0;
    if (lane<32){
      float d1 = __fsub_rn(xb[idx*CIN + 64 + lane], lc1);
      s1 += (double)d1; s2 += (double)d1*(double)d1;
    }
    if (lane<3){
      float w = __fsub_rn(zb[idx*3 + lane], czv);
      a1 += (double)w; a2 += (double)w*(double)w;
    }
  }
#pragma unroll
  for (int off=32; off>0; off>>=1){ s1 += __shfl_xor(s1,off); s2 += __shfl_xor(s2,off); }
  __shared__ double shx[4][2];
  __shared__ double shz[4][3][2];
  if (lane==0){ shx[wid][0]=s1; shx[wid][1]=s2; }
  if (lane<3){ shz[wid][lane][0]=a1; shz[wid][lane][1]=a2; }
  __syncthreads();
  if (tid==0){
    double u0=0,u1=0;
    for (int w=0;w<4;++w){ u0+=shx[w][0]; u1+=shx[w][1]; }
    double* outp = partials + (size_t)blockIdx.x*8;
    outp[0]=u0; outp[1]=u1;
    for (int axq=0; axq<3; ++axq){
      double v0=0,v1=0;
      for (int w=0;w<4;++w){ v0+=shz[w][axq][0]; v1+=shz[w][axq][1]; }
      outp[2+2*axq]=v0; outp[3+2*axq]=v1;
    }
  }
}

__global__ void finalize_kernel(const double* __restrict__ partials, float* __restrict__ scal){
  const int lane = threadIdx.x;  // 64 threads, 1 wave
  double s1=0,s2=0;
  double z0a=0,z0b=0,z1a=0,z1b=0,z2a=0,z2b=0;
  for (int i=0;i<32;++i){
    const double* p = partials + (size_t)(lane*32+i)*8;   // 32 consecutive blocks -> same b
    s1+=p[0]; s2+=p[1];
    z0a+=p[2]; z0b+=p[3]; z1a+=p[4]; z1b+=p[5]; z2a+=p[6]; z2b+=p[7];
  }
#pragma unroll
  for (int off=32; off>0; off>>=1){ s1+=__shfl_xor(s1,off); s2+=__shfl_xor(s2,off); }
#pragma unroll
  for (int off=8; off>0; off>>=1){
    z0a+=__shfl_xor(z0a,off); z0b+=__shfl_xor(z0b,off);
    z1a+=__shfl_xor(z1a,off); z1b+=__shfl_xor(z1b,off);
    z2a+=__shfl_xor(z2a,off); z2b+=__shfl_xor(z2b,off);
  }
  __shared__ double zb[4][3][2];
  if ((lane&15)==0){
    int b = lane>>4;
    zb[b][0][0]=z0a; zb[b][0][1]=z0b;
    zb[b][1][0]=z1a; zb[b][1][1]=z1b;
    zb[b][2][0]=z2a; zb[b][2][1]=z2b;
  }
  __syncthreads();
  if (lane==0){
    double nx = (double)NB*NG*NK*CIN;
    double varx = (s2 - s1*s1/nx)/(nx-1.0);
    float stdx = (float)sqrt(varx);
    double t1=0,t2=0;
    for (int b=0;b<4;++b) for (int a=0;a<3;++a){ t1+=zb[b][a][0]; t2+=zb[b][a][1]; }
    double nz = (double)NB*NG*NK*3;
    double varz = (t2 - t1*t1/nz)/(nz-1.0);
    float stdz = (float)sqrt(varz);
    float sdiv = stdz + 1e-5f;
    double n2 = (double)NG*NK;
    double acc=0.0;
    for (int b=0;b<4;++b) for (int a=0;a<3;++a){
      double v = (zb[b][a][1] - zb[b][a][0]*zb[b][a][0]/n2)/(n2-1.0);
      acc += sqrt(v);
    }
    float gstd = (float)(acc/12.0) / sdiv;   // std(x4) = std(raw)/(std_xyz+1e-5)
    float sig = 0.26f*(1.0f+gstd) + 1e-6f;
    float blend = 1.0f/(1.0f + expf(-(gstd-0.1f)*10.0f));
    scal[0] = 1.0f/(stdx + 1e-5f);
    scal[1] = 1.0f/sdiv;
    scal[2] = 1.0f/sig;
    scal[3] = blend;
  }
}

// ---------------- main fused kernel: pe + weighting + max/mean over K -> lc in d_out ----------------
__global__ __launch_bounds__(256) void main_kernel(const float* __restrict__ x, const float* __restrict__ xyz,
                                                   const int* __restrict__ fps_idx, const int* __restrict__ knn,
                                                   const float* __restrict__ scal, float* __restrict__ lc_out){
  const int tid=threadIdx.x, wid=tid>>6, lane=tid&63;
  const int pid = blockIdx.x*4 + wid;
  const int b = pid>>11, g = pid&2047;
  const float inv_x = scal[0], inv_z = scal[1], inv_sig = scal[2], blend = scal[3];
  const float omb = 1.0f - blend;
  const int fi = fps_idx[pid];
  const float* xb = x + (size_t)b*NPTS*CIN;
  const float* zb = xyz + (size_t)b*NPTS*3;
  const float cx = zb[fi*3+0], cy = zb[fi*3+1], cz = zb[fi*3+2];
  // lane's 3 channels: c = lane, 64+lane, 128+lane
  const float lcx0 = xb[fi*CIN + lane];
  const float lcx1 = (lane<32) ? xb[fi*CIN + 64 + lane] : xb[fi*CIN + lane - 32];
  const float lcx2 = xb[fi*CIN + 32 + lane];
  // r0: fourier, dim = lane>>5 (0/1), rr = lane&31, freq = rr>>1, odd->cos
  const int dim0 = lane>>5;
  const int rr0 = lane&31;
  const bool cos0 = rr0 & 1;
  const float bs0 = 100.0f / powf(1000.0f, (float)(rr0>>1) * (1.0f/16.0f));
  // r1: lane<32 fourier dim=2; lane>=32 adaptive dim=0, j=lane-32
  const bool cos1 = lane & 1;
  const float bs1 = 100.0f / powf(1000.0f, (float)((lane&31)>>1) * (1.0f/16.0f));
  const float fv1 = (float)(-1.0 + 2.0*(double)(lane-32+1)/33.0);
  // r2: adaptive, cc=32+lane: dim=cc>>5 (1/2), j=cc&31
  const int dim2 = (32+lane)>>5;
  const int j2 = (32+lane)&31;
  const float fv2 = (float)(-1.0 + 2.0*(double)(j2+1)/33.0);

  float mx0=-INFINITY, mx1=-INFINITY, mx2=-INFINITY;
  float sm0=0.f, sm1=0.f, sm2=0.f;
  for (int k=0;k<NK;++k){
    const int idx = knn[pid*NK + k];
    const float p0 = zb[idx*3+0], p1 = zb[idx*3+1], p2v = zb[idx*3+2];
    const float xn0 = (p0-cx)*inv_z, xn1 = (p1-cy)*inv_z, xn2 = (p2v-cz)*inv_z;
    const float xk0 = xb[idx*CIN + lane];
    float xk1 = 0.f; if (lane<32) xk1 = xb[idx*CIN + 64 + lane];
    { // r0
      float v = dim0 ? xn1 : xn0;
      float a = v * bs0;
      float pe = cos0 ? __cosf(a) : __sinf(a);
      float f = (xk0 - lcx0) * inv_x;
      float w = (f + pe) * pe;
      mx0 = fmaxf(mx0, w); sm0 += w;
    }
    { // r1
      float pe, f;
      if (lane < 32){
        float a = xn2 * bs1;
        pe = cos1 ? __cosf(a) : __sinf(a);
        f = (xk1 - lcx1) * inv_x;
      } else {
        float zq = (xn0 - fv1) * inv_sig;
        pe = blend * __expf(-0.5f*zq*zq) + omb * __cosf(zq);
        f = lcx1;   // raw center features (second concat half)
      }
      float w = (f + pe) * pe;
      mx1 = fmaxf(mx1, w); sm1 += w;
    }
    { // r2
      float v = (dim2==1) ? xn1 : xn2;
      float zq = (v - fv2) * inv_sig;
      float pe = blend * __expf(-0.5f*zq*zq) + omb * __cosf(zq);
      float w = (lcx2 + pe) * pe;
      mx2 = fmaxf(mx2, w); sm2 += w;
    }
  }
  const size_t obase = ((size_t)b*COUT)*NG + g;
  lc_out[obase + (size_t)lane*NG]       = mx0 + sm0*(1.0f/32.0f);
  lc_out[obase + (size_t)(64+lane)*NG]  = mx1 + sm1*(1.0f/32.0f);
  lc_out[obase + (size_t)(128+lane)*NG] = mx2 + sm2*(1.0f/32.0f);
}

// ---------------- batch-norm stats (per channel over B,G; ddof=0) ----------------
__global__ __launch_bounds__(256) void bn_stats_kernel(const float* __restrict__ lc, float* __restrict__ bn){
  const int c = blockIdx.x, t = threadIdx.x, lane=t&63, wid=t>>6;
  double s1=0.0, s2=0.0;
  for (int i=t; i<NB*NG; i+=256){
    int b=i>>11, g=i&2047;
    float v = lc[((size_t)(b*COUT)+c)*NG + g];
    s1 += (double)v; s2 += (double)v*(double)v;
  }
#pragma unroll
  for (int off=32; off>0; off>>=1){ s1+=__shfl_xor(s1,off); s2+=__shfl_xor(s2,off); }
  __shared__ double sh1[4], sh2[4];
  if (lane==0){ sh1[wid]=s1; sh2[wid]=s2; }
  __syncthreads();
  if (t==0){
    double a=sh1[0]+sh1[1]+sh1[2]+sh1[3], q=sh2[0]+sh2[1]+sh2[2]+sh2[3];
    double n=(double)(NB*NG);
    double mu=a/n, var=q/n - mu*mu;
    bn[c]=(float)mu;
    bn[COUT+c]=(float)(1.0/sqrt(var + 1e-5));
  }
}

// ---------------- final: BN affine + exact gelu, in-place on d_out ----------------
__global__ __launch_bounds__(256) void final_kernel(const float* __restrict__ bn, const float* __restrict__ gamma,
                                                    const float* __restrict__ beta, float* __restrict__ out){
  int i = blockIdx.x*256 + threadIdx.x;
  int c = (i >> 11) % COUT;
  float v = out[i];
  float y = (v - bn[c]) * bn[COUT + c];
  y = y*gamma[c] + beta[c];
  out[i] = y * 0.5f * (1.0f + erff(y * 0.70710678118654752f));
}

extern "C" void kernel_launch(void* const* d_in, const int* in_sizes, int n_in,
                              void* d_out, int out_size, void* d_ws, size_t ws_size,
                              hipStream_t stream){
  const float* xyz   = (const float*)d_in[0];
  const float* x     = (const float*)d_in[1];
  const float* gamma = (const float*)d_in[2];
  const float* beta  = (const float*)d_in[3];
  float* out = (float*)d_out;
  char* ws = (char*)d_ws;
  // workspace layout (all regions fully written before read every launch)
  int*    fps  = (int*)   (ws + 0);        //  32 KB
  int*    knn  = (int*)   (ws + 32768);    //   1 MB
  float*  xs   = (float*) (ws + 1081344);  // 128 KB
  float*  ys   = (float*) (ws + 1212416);
  float*  zs   = (float*) (ws + 1343488);
  float*  d2   = (float*) (ws + 1474560);
  double* parts= (double*)(ws + 1605632);  // 2048*8 doubles
  float*  scal = (float*) (ws + 1736704);  // 4 floats
  float*  bn   = (float*) (ws + 1736768);  // 384 floats

  (void)hipFuncSetAttribute(reinterpret_cast<const void*>(fps_kernel),
                            hipFuncAttributeMaxDynamicSharedMemorySize, FPS_LDS);

  setup_kernel   <<<dim3((NB*NPTS+255)/256), dim3(256), 0, stream>>>(xyz, xs, ys, zs, d2);
  fps_kernel     <<<dim3(NB),                dim3(512), FPS_LDS, stream>>>(xyz, fps);
  knn_kernel     <<<dim3(NB*NG/4),           dim3(256), 0, stream>>>(xs, ys, zs, d2, fps, knn);
  stats_kernel   <<<dim3(NB*NG/4),           dim3(256), 0, stream>>>(x, xyz, fps, knn, parts);
  finalize_kernel<<<dim3(1),                 dim3(64),  0, stream>>>(parts, scal);
  main_kernel    <<<dim3(NB*NG/4),           dim3(256), 0, stream>>>(x, xyz, fps, knn, scal, out);
  bn_stats_kernel<<<dim3(COUT),              dim3(256), 0, stream>>>(out, bn);
  final_kernel   <<<dim3((NB*COUT*NG)/256),  dim3(256), 0, stream>>>(bn, gamma, beta, out);
}

// Round 10
// 2452.187 us; speedup vs baseline: 1.5094x; 1.5094x over previous
//
#include <hip/hip_runtime.h>
#include <cstdint>
#include <math.h>

#define NPTS 8192
#define NB 4
#define NG 2048
#define NK 32
#define CIN 96
#define COUT 192

typedef unsigned long long ull;

// ---------------- setup: SoA transpose + |p|^2 (bit-exact vs ref dst2) ----------------
__global__ __launch_bounds__(256) void setup_kernel(const float* __restrict__ xyz,
                                                    float* __restrict__ xs, float* __restrict__ ys,
                                                    float* __restrict__ zs, float* __restrict__ d2){
  int i = blockIdx.x*256 + threadIdx.x;
  if (i >= NB*NPTS) return;
  float x = xyz[3*i+0], y = xyz[3*i+1], z = xyz[3*i+2];
  xs[i]=x; ys[i]=y; zs[i]=z;
  d2[i] = __fadd_rn(__fadd_rn(__fmul_rn(x,x),__fmul_rn(y,y)),__fmul_rn(z,z));
}

__device__ __forceinline__ ull umax64(ull a, ull b){ return (a>b)?a:b; }

// DPP u64 max reduce step (both halves moved with same ctrl -> same source lane)
template<int CTRL>
__device__ __forceinline__ ull dppmax64(ull v){
  unsigned lo=(unsigned)v, hi=(unsigned)(v>>32);
  unsigned olo=(unsigned)__builtin_amdgcn_update_dpp((int)lo,(int)lo,CTRL,0xf,0xf,false);
  unsigned ohi=(unsigned)__builtin_amdgcn_update_dpp((int)hi,(int)hi,CTRL,0xf,0xf,false);
  ull o=((ull)ohi<<32)|(ull)olo;
  return (o>v)?o:v;
}
__device__ __forceinline__ ull wavemax64(ull v){   // result valid in lane 63
  v=dppmax64<0x111>(v); v=dppmax64<0x112>(v); v=dppmax64<0x114>(v);
  v=dppmax64<0x118>(v); v=dppmax64<0x142>(v); v=dppmax64<0x143>(v);
  return v;
}

// ---------------- FPS: LEAN brute force. 512 threads, 16 reg pts/lane, 2047 rounds ----
// Consolidation of R2..R9 learnings: every pruning variant lost to the minimal round
// (prune -> imbalance or fixed overhead under barrier lockstep). Per round:
//   16 register updates -> in-lane u64 tree (15 umax64) -> 6-step DPP wavemax64 ->
//   lane63 8B write to double-buffered keys[it&1][w] (no atomics) -> ONE barrier ->
//   8-key tree -> winner coords via broadcast ds_read_b128 from identity ctab.
// key = (D_bits<<32) | (8191-p): u64 max == (max dist, lowest orig index) == np.argmax.
__global__ __launch_bounds__(512,2) void fps_kernel(const float* __restrict__ xyz, int* __restrict__ fps_idx){
#pragma clang fp contract(off)   // selection-critical: no fma contraction anywhere here
  extern __shared__ char smem[];
  float4* ctab = (float4*)smem;                 // 8192*16 = 131072 B, identity layout
  ull*    keys = (ull*)(smem + 131072);         // [2][8]
  const int b = blockIdx.x, t = threadIdx.x;
  const int w = t>>6, lane = t&63;
  const float* base = xyz + (size_t)b*NPTS*3;
  float px[16], py[16], pz[16], D[16];
  unsigned kc[16];                              // 8191 - p  (tie-break constant)
#pragma unroll
  for (int j=0;j<16;++j){
    int p = t + 512*j;                          // coalesced global reads
    float x=base[3*p+0], y=base[3*p+1], z=base[3*p+2];
    px[j]=x; py[j]=y; pz[j]=z;
    D[j]=1e10f;                                 // ref init
    kc[j]=8191u-(unsigned)p;
    ctab[p] = make_float4(x,y,z,0.f);           // identity scatter: conflict-free b128
  }
  if (t==0) fps_idx[b*NG]=0;
  __syncthreads();
  float lx=base[0], ly=base[1], lz=base[2];     // seed = point 0
  for (int it=0; it<NG-1; ++it){
    // update D (rn mul/add, same order as np) and build per-slot keys
    ull K[16];
#pragma unroll
    for (int j=0;j<16;++j){
      float dx=px[j]-lx, dy=py[j]-ly, dz=pz[j]-lz;
      float d=(dx*dx+dy*dy)+dz*dz;
      float Dn=fminf(D[j],d);
      D[j]=Dn;
      K[j]=(((ull)__float_as_uint(Dn))<<32)|(ull)kc[j];
    }
    // in-lane tree (depth 4, ILP-rich)
#pragma unroll
    for (int s=8;s>0;s>>=1)
#pragma unroll
      for (int j=0;j<16;++j) if (j<s) K[j]=umax64(K[j],K[j+s]);
    ull P = wavemax64(K[0]);                    // lane63 = wave best
    if (lane==63) keys[(it&1)*8 + w] = P;
    __syncthreads();                            // ONE barrier per round
    const ull* kk = keys + (it&1)*8;
    ull k0=umax64(kk[0],kk[1]), k1=umax64(kk[2],kk[3]);
    ull k2=umax64(kk[4],kk[5]), k3=umax64(kk[6],kk[7]);
    ull k = umax64(umax64(k0,k1),umax64(k2,k3));
    unsigned pw = 8191u - (unsigned)(k & 0xffffffffu);   // winner flat index
    float4 c4 = ctab[pw];                       // broadcast ds_read_b128
    lx=c4.x; ly=c4.y; lz=c4.z;
    if (t==0) fps_idx[b*NG + it + 1] = (int)pw;
  }
}

// ---------------- kNN: wave-wide exact top-32 (lexicographic (d,idx)) ----------------
__device__ __forceinline__ bool lexlt(float ad, int ai, float bd, int bi){
  return (ad < bd) || ((ad == bd) && (ai < bi));
}
__device__ __forceinline__ void sort_desc(float& d, int& i, int lane){
#pragma unroll
  for (int k=2;k<=64;k<<=1){
#pragma unroll
    for (int j=k>>1;j>0;j>>=1){
      float od = __shfl_xor(d, j);
      int   oi = __shfl_xor(i, j);
      bool dirUp = (lane & k) != 0;      // flipped -> overall descending
      bool lower = (lane & j) == 0;
      bool less  = lexlt(d,i,od,oi);
      bool keep  = (less == (lower == dirUp));
      if (!keep){ d=od; i=oi; }
    }
  }
}
__device__ __forceinline__ void merge_asc(float& d, int& i, int lane){
#pragma unroll
  for (int j=32;j>0;j>>=1){
    float od = __shfl_xor(d, j);
    int   oi = __shfl_xor(i, j);
    bool lower = (lane & j) == 0;
    bool less  = lexlt(d,i,od,oi);
    bool keep  = (less == lower);
    if (!keep){ d=od; i=oi; }
  }
}

__global__ __launch_bounds__(256) void knn_kernel(const float* __restrict__ xs, const float* __restrict__ ys,
                                                  const float* __restrict__ zs, const float* __restrict__ d2,
                                                  const int* __restrict__ fps_idx, int* __restrict__ knn_out){
  __shared__ float tx[256], ty[256], tz[256], td[256];
  const int tid = threadIdx.x;
  const int wid = tid>>6, lane = tid&63;
  const int pid = blockIdx.x*4 + wid;     // b*NG+g
  const int b = pid >> 11;
  const float* bx = xs + b*NPTS;
  const float* by = ys + b*NPTS;
  const float* bz = zs + b*NPTS;
  const float* bD = d2 + b*NPTS;
  const int fi = fps_idx[pid];
  const float ax = bx[fi], ay = by[fi], az = bz[fi];
  const float src2 = __fadd_rn(__fadd_rn(__fmul_rn(ax,ax),__fmul_rn(ay,ay)),__fmul_rn(az,az));
  float Ad = INFINITY; int Ai = 0x7fffffff;      // sorted-ascending top-64 (1/lane)
  float tau_d = INFINITY; int tau_i = 0x7fffffff; // current exact 32nd smallest
  for (int s=0; s<NPTS/256; ++s){
    __syncthreads();
    int gidx = s*256 + tid;
    tx[tid]=bx[gidx]; ty[tid]=by[gidx]; tz[tid]=bz[gidx]; td[tid]=bD[gidx];
    __syncthreads();
    float m0,m1,m2,m3; int i0,i1,i2,i3;
#define LOADJ(mj, ij, J) { int li = (J)*64 + lane; \
    float dot = __fadd_rn(__fadd_rn(__fmul_rn(ax,tx[li]),__fmul_rn(ay,ty[li])),__fmul_rn(az,tz[li])); \
    mj = __fadd_rn(__fadd_rn(__fmul_rn(-2.0f,dot), src2), td[li]); ij = s*256 + li; }
    LOADJ(m0,i0,0) LOADJ(m1,i1,1) LOADJ(m2,i2,2) LOADJ(m3,i3,3)
#undef LOADJ
    while (true){
      bool any = lexlt(m0,i0,tau_d,tau_i) || lexlt(m1,i1,tau_d,tau_i) ||
                 lexlt(m2,i2,tau_d,tau_i) || lexlt(m3,i3,tau_d,tau_i);
      if (__ballot(any) == 0ull) break;
      float cd = m0; int ci = i0; int sel = 0;
      if (lexlt(m1,i1,cd,ci)){ cd=m1; ci=i1; sel=1; }
      if (lexlt(m2,i2,cd,ci)){ cd=m2; ci=i2; sel=2; }
      if (lexlt(m3,i3,cd,ci)){ cd=m3; ci=i3; sel=3; }
      if      (sel==0) m0=INFINITY;
      else if (sel==1) m1=INFINITY;
      else if (sel==2) m2=INFINITY;
      else             m3=INFINITY;
      sort_desc(cd, ci, lane);                    // new chunk descending
      if (lexlt(cd,ci,Ad,Ai)){ Ad=cd; Ai=ci; }    // elementwise min -> bitonic
      merge_asc(Ad, Ai, lane);                    // re-sort ascending
      tau_d = __shfl(Ad, 31);
      tau_i = __shfl(Ai, 31);
    }
  }
  if (lane < NK) knn_out[pid*NK + lane] = Ai;
}

// ---------------- global stats (fp64 partials per block) ----------------
__global__ __launch_bounds__(256) void stats_kernel(const float* __restrict__ x, const float* __restrict__ xyz,
                                                    const int* __restrict__ fps_idx, const int* __restrict__ knn,
                                                    double* __restrict__ partials){
  const int tid=threadIdx.x, wid=tid>>6, lane=tid&63;
  const int pid = blockIdx.x*4 + wid;
  const int b = pid>>11;
  const int fi = fps_idx[pid];
  const float* xb = x + (size_t)b*NPTS*CIN;
  const float* zb = xyz + (size_t)b*NPTS*3;
  const float lc0 = xb[fi*CIN + lane];
  float lc1 = 0.f; if (lane<32) lc1 = xb[fi*CIN + 64 + lane];
  float czv = 0.f; if (lane<3)  czv = zb[fi*3 + lane];
  double s1=0.0, s2=0.0, a1=0.0, a2=0.0;
  for (int k=0;k<NK;++k){
    int idx = knn[pid*NK + k];
    float d0 = __fsub_rn(xb[idx*CIN + lane], lc0);
    s1 += (double)d0; s2 += (double)d0*(double)d0;
    if (lane<32){
      float d1 = __fsub_rn(xb[idx*CIN + 64 + lane], lc1);
      s1 += (double)d1; s2 += (double)d1*(double)d1;
    }
    if (lane<3){
      float w = __fsub_rn(zb[idx*3 + lane], czv);
      a1 += (double)w; a2 += (double)w*(double)w;
    }
  }
#pragma unroll
  for (int off=32; off>0; off>>=1){ s1 += __shfl_xor(s1,off); s2 += __shfl_xor(s2,off); }
  __shared__ double shx[4][2];
  __shared__ double shz[4][3][2];
  if (lane==0){ shx[wid][0]=s1; shx[wid][1]=s2; }
  if (lane<3){ shz[wid][lane][0]=a1; shz[wid][lane][1]=a2; }
  __syncthreads();
  if (tid==0){
    double u0=0,u1=0;
    for (int w=0;w<4;++w){ u0+=shx[w][0]; u1+=shx[w][1]; }
    double* outp = partials + (size_t)blockIdx.x*8;
    outp[0]=u0; outp[1]=u1;
    for (int axq=0; axq<3; ++axq){
      double v0=0,v1=0;
      for (int w=0;w<4;++w){ v0+=shz[w][axq][0]; v1+=shz[w][axq][1]; }
      outp[2+2*axq]=v0; outp[3+2*axq]=v1;
    }
  }
}

__global__ void finalize_kernel(const double* __restrict__ partials, float* __restrict__ scal){
  const int lane = threadIdx.x;  // 64 threads, 1 wave
  double s1=0,s2=0;
  double z0a=0,z0b=0,z1a=0,z1b=0,z2a=0,z2b=0;
  for (int i=0;i<32;++i){
    const double* p = partials + (size_t)(lane*32+i)*8;   // 32 consecutive blocks -> same b
    s1+=p[0]; s2+=p[1];
    z0a+=p[2]; z0b+=p[3]; z1a+=p[4]; z1b+=p[5]; z2a+=p[6]; z2b+=p[7];
  }
#pragma unroll
  for (int off=32; off>0; off>>=1){ s1+=__shfl_xor(s1,off); s2+=__shfl_xor(s2,off); }
#pragma unroll
  for (int off=8; off>0; off>>=1){
    z0a+=__shfl_xor(z0a,off); z0b+=__shfl_xor(z0b,off);
    z1a+=__shfl_xor(z1a,off); z1b+=__shfl_xor(z1b,off);
    z2a+=__shfl_xor(z2a,off); z2b+=__shfl_xor(z2b,off);
  }
  __shared__ double zb[4][3][2];
  if ((lane&15)==0){
    int b = lane>>4;
    zb[b][0][0]=z0a; zb[b][0][1]=z0b;
    zb[b][1][0]=z1a; zb[b][1][1]=z1b;
    zb[b][2][0]=z2a; zb[b][2][1]=z2b;
  }
  __syncthreads();
  if (lane==0){
    double nx = (double)NB*NG*NK*CIN;
    double varx = (s2 - s1*s1/nx)/(nx-1.0);
    float stdx = (float)sqrt(varx);
    double t1=0,t2=0;
    for (int b=0;b<4;++b) for (int a=0;a<3;++a){ t1+=zb[b][a][0]; t2+=zb[b][a][1]; }
    double nz = (double)NB*NG*NK*3;
    double varz = (t2 - t1*t1/nz)/(nz-1.0);
    float stdz = (float)sqrt(varz);
    float sdiv = stdz + 1e-5f;
    double n2 = (double)NG*NK;
    double acc=0.0;
    for (int b=0;b<4;++b) for (int a=0;a<3;++a){
      double v = (zb[b][a][1] - zb[b][a][0]*zb[b][a][0]/n2)/(n2-1.0);
      acc += sqrt(v);
    }
    float gstd = (float)(acc/12.0) / sdiv;   // std(x4) = std(raw)/(std_xyz+1e-5)
    float sig = 0.26f*(1.0f+gstd) + 1e-6f;
    float blend = 1.0f/(1.0f + expf(-(gstd-0.1f)*10.0f));
    scal[0] = 1.0f/(stdx + 1e-5f);
    scal[1] = 1.0f/sdiv;
    scal[2] = 1.0f/sig;
    scal[3] = blend;
  }
}

// ---------------- main fused kernel: pe + weighting + max/mean over K -> lc in d_out ----------------
__global__ __launch_bounds__(256) void main_kernel(const float* __restrict__ x, const float* __restrict__ xyz,
                                                   const int* __restrict__ fps_idx, const int* __restrict__ knn,
                                                   const float* __restrict__ scal, float* __restrict__ lc_out){
  const int tid=threadIdx.x, wid=tid>>6, lane=tid&63;
  const int pid = blockIdx.x*4 + wid;
  const int b = pid>>11, g = pid&2047;
  const float inv_x = scal[0], inv_z = scal[1], inv_sig = scal[2], blend = scal[3];
  const float omb = 1.0f - blend;
  const int fi = fps_idx[pid];
  const float* xb = x + (size_t)b*NPTS*CIN;
  const float* zb = xyz + (size_t)b*NPTS*3;
  const float cx = zb[fi*3+0], cy = zb[fi*3+1], cz = zb[fi*3+2];
  // lane's 3 channels: c = lane, 64+lane, 128+lane
  const float lcx0 = xb[fi*CIN + lane];
  const float lcx1 = (lane<32) ? xb[fi*CIN + 64 + lane] : xb[fi*CIN + lane - 32];
  const float lcx2 = xb[fi*CIN + 32 + lane];
  // r0: fourier, dim = lane>>5 (0/1), rr = lane&31, freq = rr>>1, odd->cos
  const int dim0 = lane>>5;
  const int rr0 = lane&31;
  const bool cos0 = rr0 & 1;
  const float bs0 = 100.0f / powf(1000.0f, (float)(rr0>>1) * (1.0f/16.0f));
  // r1: lane<32 fourier dim=2; lane>=32 adaptive dim=0, j=lane-32
  const bool cos1 = lane & 1;
  const float bs1 = 100.0f / powf(1000.0f, (float)((lane&31)>>1) * (1.0f/16.0f));
  const float fv1 = (float)(-1.0 + 2.0*(double)(lane-32+1)/33.0);
  // r2: adaptive, cc=32+lane: dim=cc>>5 (1/2), j=cc&31
  const int dim2 = (32+lane)>>5;
  const int j2 = (32+lane)&31;
  const float fv2 = (float)(-1.0 + 2.0*(double)(j2+1)/33.0);

  float mx0=-INFINITY, mx1=-INFINITY, mx2=-INFINITY;
  float sm0=0.f, sm1=0.f, sm2=0.f;
  for (int k=0;k<NK;++k){
    const int idx = knn[pid*NK + k];
    const float p0 = zb[idx*3+0], p1 = zb[idx*3+1], p2v = zb[idx*3+2];
    const float xn0 = (p0-cx)*inv_z, xn1 = (p1-cy)*inv_z, xn2 = (p2v-cz)*inv_z;
    const float xk0 = xb[idx*CIN + lane];
    float xk1 = 0.f; if (lane<32) xk1 = xb[idx*CIN + 64 + lane];
    { // r0
      float v = dim0 ? xn1 : xn0;
      float a = v * bs0;
      float pe = cos0 ? __cosf(a) : __sinf(a);
      float f = (xk0 - lcx0) * inv_x;
      float w = (f + pe) * pe;
      mx0 = fmaxf(mx0, w); sm0 += w;
    }
    { // r1
      float pe, f;
      if (lane < 32){
        float a = xn2 * bs1;
        pe = cos1 ? __cosf(a) : __sinf(a);
        f = (xk1 - lcx1) * inv_x;
      } else {
        float zq = (xn0 - fv1) * inv_sig;
        pe = blend * __expf(-0.5f*zq*zq) + omb * __cosf(zq);
        f = lcx1;   // raw center features (second concat half)
      }
      float w = (f + pe) * pe;
      mx1 = fmaxf(mx1, w); sm1 += w;
    }
    { // r2
      float v = (dim2==1) ? xn1 : xn2;
      float zq = (v - fv2) * inv_sig;
      float pe = blend * __expf(-0.5f*zq*zq) + omb * __cosf(zq);
      float w = (lcx2 + pe) * pe;
      mx2 = fmaxf(mx2, w); sm2 += w;
    }
  }
  const size_t obase = ((size_t)b*COUT)*NG + g;
  lc_out[obase + (size_t)lane*NG]       = mx0 + sm0*(1.0f/32.0f);
  lc_out[obase + (size_t)(64+lane)*NG]  = mx1 + sm1*(1.0f/32.0f);
  lc_out[obase + (size_t)(128+lane)*NG] = mx2 + sm2*(1.0f/32.0f);
}

// ---------------- batch-norm stats (per channel over B,G; ddof=0) ----------------
__global__ __launch_bounds__(256) void bn_stats_kernel(const float* __restrict__ lc, float* __restrict__ bn){
  const int c = blockIdx.x, t = threadIdx.x, lane=t&63, wid=t>>6;
  double s1=0.0, s2=0.0;
  for (int i=t; i<NB*NG; i+=256){
    int b=i>>11, g=i&2047;
    float v = lc[((size_t)(b*COUT)+c)*NG + g];
    s1 += (double)v; s2 += (double)v*(double)v;
  }
#pragma unroll
  for (int off=32; off>0; off>>=1){ s1+=__shfl_xor(s1,off); s2+=__shfl_xor(s2,off); }
  __shared__ double sh1[4], sh2[4];
  if (lane==0){ sh1[wid]=s1; sh2[wid]=s2; }
  __syncthreads();
  if (t==0){
    double a=sh1[0]+sh1[1]+sh1[2]+sh1[3], q=sh2[0]+sh2[1]+sh2[2]+sh2[3];
    double n=(double)(NB*NG);
    double mu=a/n, var=q/n - mu*mu;
    bn[c]=(float)mu;
    bn[COUT+c]=(float)(1.0/sqrt(var + 1e-5));
  }
}

// ---------------- final: BN affine + exact gelu, in-place on d_out ----------------
__global__ __launch_bounds__(256) void final_kernel(const float* __restrict__ bn, const float* __restrict__ gamma,
                                                    const float* __restrict__ beta, float* __restrict__ out){
  int i = blockIdx.x*256 + threadIdx.x;
  int c = (i >> 11) % COUT;
  float v = out[i];
  float y = (v - bn[c]) * bn[COUT + c];
  y = y*gamma[c] + beta[c];
  out[i] = y * 0.5f * (1.0f + erff(y * 0.70710678118654752f));
}

extern "C" void kernel_launch(void* const* d_in, const int* in_sizes, int n_in,
                              void* d_out, int out_size, void* d_ws, size_t ws_size,
                              hipStream_t stream){
  const float* xyz   = (const float*)d_in[0];
  const float* x     = (const float*)d_in[1];
  const float* gamma = (const float*)d_in[2];
  const float* beta  = (const float*)d_in[3];
  float* out = (float*)d_out;
  char* ws = (char*)d_ws;
  // workspace layout (all regions fully written before read every launch)
  int*    fps  = (int*)   (ws + 0);        //  32 KB
  int*    knn  = (int*)   (ws + 32768);    //   1 MB
  float*  xs   = (float*) (ws + 1081344);  // 128 KB
  float*  ys   = (float*) (ws + 1212416);
  float*  zs   = (float*) (ws + 1343488);
  float*  d2   = (float*) (ws + 1474560);
  double* parts= (double*)(ws + 1605632);  // 2048*8 doubles
  float*  scal = (float*) (ws + 1736704);  // 4 floats
  float*  bn   = (float*) (ws + 1736768);  // 384 floats

  const int fps_lds = 131072 + 128;        // ctab + double-buffered 8 wave keys
  (void)hipFuncSetAttribute(reinterpret_cast<const void*>(fps_kernel),
                            hipFuncAttributeMaxDynamicSharedMemorySize, fps_lds);

  setup_kernel   <<<dim3((NB*NPTS+255)/256), dim3(256), 0, stream>>>(xyz, xs, ys, zs, d2);
  fps_kernel     <<<dim3(NB),                dim3(512), fps_lds, stream>>>(xyz, fps);
  knn_kernel     <<<dim3(NB*NG/4),           dim3(256), 0, stream>>>(xs, ys, zs, d2, fps, knn);
  stats_kernel   <<<dim3(NB*NG/4),           dim3(256), 0, stream>>>(x, xyz, fps, knn, parts);
  finalize_kernel<<<dim3(1),                 dim3(64),  0, stream>>>(parts, scal);
  main_kernel    <<<dim3(NB*NG/4),           dim3(256), 0, stream>>>(x, xyz, fps, knn, scal, out);
  bn_stats_kernel<<<dim3(COUT),              dim3(256), 0, stream>>>(out, bn);
  final_kernel   <<<dim3((NB*COUT*NG)/256),  dim3(256), 0, stream>>>(bn, gamma, beta, out);
}